// Round 1
// baseline (762.089 us; speedup 1.0000x reference)
//
#include <hip/hip_runtime.h>
#include <math.h>

#define D 128

// ---------------------------------------------------------------------------
// GEMM: O_w = X @ W_w + b_w for the 4 weights (Q,K,V,Skip) of one layer.
// X: [n,128] row-major. W: [128,128] row-major (k-major). O: [n,128].
// Block tile 64 rows x 128 cols, 256 threads, 8x4 micro-tile. blockIdx.y
// selects which of the 4 weight/output sets this block computes.
// ---------------------------------------------------------------------------
__global__ __launch_bounds__(256)
void gemm4(const float* __restrict__ X, int n,
           const float* __restrict__ Wq, const float* __restrict__ bq, float* __restrict__ Oq,
           const float* __restrict__ Wk, const float* __restrict__ bk, float* __restrict__ Ok,
           const float* __restrict__ Wv, const float* __restrict__ bv, float* __restrict__ Ov,
           const float* __restrict__ Ws, const float* __restrict__ bs, float* __restrict__ Os)
{
    const float* W; const float* b; float* O;
    switch (blockIdx.y) {
        case 0:  W = Wq; b = bq; O = Oq; break;
        case 1:  W = Wk; b = bk; O = Ok; break;
        case 2:  W = Wv; b = bv; O = Ov; break;
        default: W = Ws; b = bs; O = Os; break;
    }

    __shared__ float Xs[16][64];    // [k][row]  (transposed for vector reads)
    __shared__ float Wt[16][128];   // [k][col]

    const int tid  = threadIdx.x;
    const int trow = tid >> 5;      // 0..7
    const int tcol = tid & 31;      // 0..31
    const int r0   = trow * 8;      // 8 rows per thread
    const int c0   = tcol * 4;      // 4 cols per thread
    const int rowBase = blockIdx.x * 64;

    float acc[8][4];
    #pragma unroll
    for (int r = 0; r < 8; ++r)
        #pragma unroll
        for (int j = 0; j < 4; ++j) acc[r][j] = 0.f;

    for (int k0 = 0; k0 < D; k0 += 16) {
        // stage X tile 64x16 (transposed into Xs[k][row])
        {
            int r = tid >> 2;           // 0..63
            int q = tid & 3;            // 0..3
            int row = rowBase + r;
            float4 xv = make_float4(0.f, 0.f, 0.f, 0.f);
            if (row < n) xv = *(const float4*)&X[row * D + k0 + q * 4];
            Xs[q*4+0][r] = xv.x; Xs[q*4+1][r] = xv.y;
            Xs[q*4+2][r] = xv.z; Xs[q*4+3][r] = xv.w;
        }
        // stage W tile 16x128 (2 float4s per thread)
        {
            #pragma unroll
            for (int i = 0; i < 2; ++i) {
                int f4 = tid * 2 + i;            // 0..511
                int kk = f4 >> 5;                // 0..15
                int c  = (f4 & 31) * 4;          // 0..124
                *(float4*)&Wt[kk][c] = *(const float4*)&W[(k0 + kk) * D + c];
            }
        }
        __syncthreads();

        #pragma unroll
        for (int kk = 0; kk < 16; ++kk) {
            float4 a0 = *(const float4*)&Xs[kk][r0];
            float4 a1 = *(const float4*)&Xs[kk][r0 + 4];
            float4 wv = *(const float4*)&Wt[kk][c0];
            float a[8] = {a0.x, a0.y, a0.z, a0.w, a1.x, a1.y, a1.z, a1.w};
            float w[4] = {wv.x, wv.y, wv.z, wv.w};
            #pragma unroll
            for (int r = 0; r < 8; ++r)
                #pragma unroll
                for (int j = 0; j < 4; ++j)
                    acc[r][j] += a[r] * w[j];
        }
        __syncthreads();
    }

    const float b0 = b[c0], b1 = b[c0+1], b2 = b[c0+2], b3 = b[c0+3];
    #pragma unroll
    for (int r = 0; r < 8; ++r) {
        int row = rowBase + r0 + r;
        if (row < n) {
            float4 o = make_float4(acc[r][0] + b0, acc[r][1] + b1,
                                   acc[r][2] + b2, acc[r][3] + b3);
            *(float4*)&O[row * D + c0] = o;
        }
    }
}

// ---------------------------------------------------------------------------
// CSR build: in-degree histogram -> exclusive scan -> scatter src ids
// ---------------------------------------------------------------------------
__global__ void degree_hist(const int* __restrict__ dst, int e, int* __restrict__ cnt)
{
    int i = blockIdx.x * blockDim.x + threadIdx.x;
    if (i < e) atomicAdd(&cnt[dst[i]], 1);
}

__global__ __launch_bounds__(256)
void scan_kernel(const int* __restrict__ cnt, int* __restrict__ row_ptr, int n, int e)
{
    __shared__ int sm[256];
    __shared__ int run;
    if (threadIdx.x == 0) run = 0;
    __syncthreads();
    for (int base = 0; base < n; base += 256) {
        int i = base + threadIdx.x;
        int v = (i < n) ? cnt[i] : 0;
        sm[threadIdx.x] = v;
        __syncthreads();
        int acc = v;
        for (int off = 1; off < 256; off <<= 1) {
            int t = (threadIdx.x >= off) ? sm[threadIdx.x - off] : 0;
            __syncthreads();
            acc += t;
            sm[threadIdx.x] = acc;
            __syncthreads();
        }
        if (i < n) row_ptr[i] = run + acc - v;   // exclusive
        __syncthreads();
        if (threadIdx.x == 0) run += sm[255];
        __syncthreads();
    }
    if (threadIdx.x == 0) row_ptr[n] = e;
}

__global__ void scatter_kernel(const int* __restrict__ src, const int* __restrict__ dst, int e,
                               const int* __restrict__ row_ptr, int* __restrict__ cursor,
                               int* __restrict__ csr_src)
{
    int i = blockIdx.x * blockDim.x + threadIdx.x;
    if (i < e) {
        int d = dst[i];
        int pos = atomicAdd(&cursor[d], 1);
        csr_src[row_ptr[d] + pos] = src[i];
    }
}

// ---------------------------------------------------------------------------
// Attention: one block (128 threads) per destination node.
// thread = output channel; wave 0 = head 0 (ch 0..63), wave 1 = head 1.
// Online softmax over incoming edges, accumulator in registers, no atomics.
// ---------------------------------------------------------------------------
__global__ __launch_bounds__(128)
void attn(const float* __restrict__ Q, const float* __restrict__ K,
          const float* __restrict__ V, const float* __restrict__ S,
          const int* __restrict__ row_ptr, const int* __restrict__ csr_src,
          float* __restrict__ out, int n, int do_relu)
{
    const int dstn = blockIdx.x;
    const int c = threadIdx.x;
    const float q = Q[dstn * D + c];
    const int beg = row_ptr[dstn];
    const int end = row_ptr[dstn + 1];

    float m = -INFINITY, l = 0.f, acc = 0.f;
    for (int i = beg; i < end; ++i) {
        int s = csr_src[i];
        float kv = K[s * D + c];
        float part = q * kv;
        #pragma unroll
        for (int off = 32; off >= 1; off >>= 1)
            part += __shfl_xor(part, off, 64);
        float alpha = part * 0.125f;              // / sqrt(64)
        float mn = fmaxf(m, alpha);
        float p = __expf(alpha - mn);
        float corr = __expf(m - mn);              // exp(-inf)=0 handles first iter
        float vv = V[s * D + c];
        l = l * corr + p;
        acc = acc * corr + p * vv;
        m = mn;
    }
    float res = (l > 0.f) ? (acc / l) : 0.f;      // empty segment -> 0 (matches JAX)
    res += S[dstn * D + c];
    if (do_relu) res = fmaxf(res, 0.f);
    out[dstn * D + c] = res;
}

// ---------------------------------------------------------------------------
extern "C" void kernel_launch(void* const* d_in, const int* in_sizes, int n_in,
                              void* d_out, int out_size, void* d_ws, size_t ws_size,
                              hipStream_t stream)
{
    const float* x    = (const float*)d_in[0];
    const int*   edge = (const int*)d_in[1];
    const int n = in_sizes[0] / D;
    const int e = in_sizes[1] / 2;
    const int* srcv = edge;
    const int* dstv = edge + e;

    const float* Wq1 = (const float*)d_in[2];  const float* bq1 = (const float*)d_in[3];
    const float* Wk1 = (const float*)d_in[4];  const float* bk1 = (const float*)d_in[5];
    const float* Wv1 = (const float*)d_in[6];  const float* bv1 = (const float*)d_in[7];
    const float* Ws1 = (const float*)d_in[8];  const float* bs1 = (const float*)d_in[9];
    const float* Wq2 = (const float*)d_in[10]; const float* bq2 = (const float*)d_in[11];
    const float* Wk2 = (const float*)d_in[12]; const float* bk2 = (const float*)d_in[13];
    const float* Wv2 = (const float*)d_in[14]; const float* bv2 = (const float*)d_in[15];
    const float* Ws2 = (const float*)d_in[16]; const float* bs2 = (const float*)d_in[17];

    // workspace layout
    char* wsb = (char*)d_ws;
    size_t off = 0;
    auto alloc = [&](size_t bytes) -> void* {
        void* p = wsb + off;
        off += (bytes + 255) & ~(size_t)255;
        return p;
    };
    float* Qb  = (float*)alloc((size_t)n * D * sizeof(float));
    float* Kb  = (float*)alloc((size_t)n * D * sizeof(float));
    float* Vb  = (float*)alloc((size_t)n * D * sizeof(float));
    float* Sb  = (float*)alloc((size_t)n * D * sizeof(float));
    float* Hb  = (float*)alloc((size_t)n * D * sizeof(float));
    int* cnt     = (int*)alloc((size_t)n * sizeof(int));
    int* cursor  = (int*)alloc((size_t)n * sizeof(int));
    int* row_ptr = (int*)alloc((size_t)(n + 1) * sizeof(int));
    int* csr_src = (int*)alloc((size_t)e * sizeof(int));
    (void)ws_size; (void)n_in; (void)out_size;

    // ---- CSR build (shared by both layers) ----
    hipMemsetAsync(cnt, 0, (size_t)n * sizeof(int), stream);
    hipMemsetAsync(cursor, 0, (size_t)n * sizeof(int), stream);
    degree_hist<<<(e + 255) / 256, 256, 0, stream>>>(dstv, e, cnt);
    scan_kernel<<<1, 256, 0, stream>>>(cnt, row_ptr, n, e);
    scatter_kernel<<<(e + 255) / 256, 256, 0, stream>>>(srcv, dstv, e, row_ptr, cursor, csr_src);

    dim3 ggrid((n + 63) / 64, 4);

    // ---- layer 1 ----
    gemm4<<<ggrid, 256, 0, stream>>>(x, n,
        Wq1, bq1, Qb, Wk1, bk1, Kb, Wv1, bv1, Vb, Ws1, bs1, Sb);
    attn<<<n, 128, 0, stream>>>(Qb, Kb, Vb, Sb, row_ptr, csr_src, Hb, n, 1);

    // ---- layer 2 ----
    gemm4<<<ggrid, 256, 0, stream>>>(Hb, n,
        Wq2, bq2, Qb, Wk2, bk2, Kb, Wv2, bv2, Vb, Ws2, bs2, Sb);
    attn<<<n, 128, 0, stream>>>(Qb, Kb, Vb, Sb, row_ptr, csr_src, (float*)d_out, n, 0);
}

// Round 2
// 600.934 us; speedup vs baseline: 1.2682x; 1.2682x over previous
//
#include <hip/hip_runtime.h>
#include <math.h>

#define D 128

// ---------------------------------------------------------------------------
// GEMM: O_w = X @ W_w + b_w for the 4 weights (Q,K,V,Skip) of one layer.
// X: [n,128] row-major. W: [128,128] row-major (k-major). O: [n,128].
// Block tile 64 rows x 128 cols, 256 threads, 8x4 micro-tile. blockIdx.y
// selects which of the 4 weight/output sets this block computes.
// ---------------------------------------------------------------------------
__global__ __launch_bounds__(256)
void gemm4(const float* __restrict__ X, int n,
           const float* __restrict__ Wq, const float* __restrict__ bq, float* __restrict__ Oq,
           const float* __restrict__ Wk, const float* __restrict__ bk, float* __restrict__ Ok,
           const float* __restrict__ Wv, const float* __restrict__ bv, float* __restrict__ Ov,
           const float* __restrict__ Ws, const float* __restrict__ bs, float* __restrict__ Os)
{
    const float* W; const float* b; float* O;
    switch (blockIdx.y) {
        case 0:  W = Wq; b = bq; O = Oq; break;
        case 1:  W = Wk; b = bk; O = Ok; break;
        case 2:  W = Wv; b = bv; O = Ov; break;
        default: W = Ws; b = bs; O = Os; break;
    }

    __shared__ float Xs[16][64];    // [k][row]  (transposed for vector reads)
    __shared__ float Wt[16][128];   // [k][col]

    const int tid  = threadIdx.x;
    const int trow = tid >> 5;      // 0..7
    const int tcol = tid & 31;      // 0..31
    const int r0   = trow * 8;      // 8 rows per thread
    const int c0   = tcol * 4;      // 4 cols per thread
    const int rowBase = blockIdx.x * 64;

    float acc[8][4];
    #pragma unroll
    for (int r = 0; r < 8; ++r)
        #pragma unroll
        for (int j = 0; j < 4; ++j) acc[r][j] = 0.f;

    for (int k0 = 0; k0 < D; k0 += 16) {
        // stage X tile 64x16 (transposed into Xs[k][row])
        {
            int r = tid >> 2;           // 0..63
            int q = tid & 3;            // 0..3
            int row = rowBase + r;
            float4 xv = make_float4(0.f, 0.f, 0.f, 0.f);
            if (row < n) xv = *(const float4*)&X[row * D + k0 + q * 4];
            Xs[q*4+0][r] = xv.x; Xs[q*4+1][r] = xv.y;
            Xs[q*4+2][r] = xv.z; Xs[q*4+3][r] = xv.w;
        }
        // stage W tile 16x128 (2 float4s per thread)
        {
            #pragma unroll
            for (int i = 0; i < 2; ++i) {
                int f4 = tid * 2 + i;            // 0..511
                int kk = f4 >> 5;                // 0..15
                int c  = (f4 & 31) * 4;          // 0..124
                *(float4*)&Wt[kk][c] = *(const float4*)&W[(k0 + kk) * D + c];
            }
        }
        __syncthreads();

        #pragma unroll
        for (int kk = 0; kk < 16; ++kk) {
            float4 a0 = *(const float4*)&Xs[kk][r0];
            float4 a1 = *(const float4*)&Xs[kk][r0 + 4];
            float4 wv = *(const float4*)&Wt[kk][c0];
            float a[8] = {a0.x, a0.y, a0.z, a0.w, a1.x, a1.y, a1.z, a1.w};
            float w[4] = {wv.x, wv.y, wv.z, wv.w};
            #pragma unroll
            for (int r = 0; r < 8; ++r)
                #pragma unroll
                for (int j = 0; j < 4; ++j)
                    acc[r][j] += a[r] * w[j];
        }
        __syncthreads();
    }

    const float b0 = b[c0], b1 = b[c0+1], b2 = b[c0+2], b3 = b[c0+3];
    #pragma unroll
    for (int r = 0; r < 8; ++r) {
        int row = rowBase + r0 + r;
        if (row < n) {
            float4 o = make_float4(acc[r][0] + b0, acc[r][1] + b1,
                                   acc[r][2] + b2, acc[r][3] + b3);
            *(float4*)&O[row * D + c0] = o;
        }
    }
}

// ---------------------------------------------------------------------------
// CSR build: in-degree histogram -> 3-phase parallel exclusive scan -> scatter
// ---------------------------------------------------------------------------
__global__ void degree_hist(const int* __restrict__ dst, int e, int* __restrict__ cnt)
{
    int i = blockIdx.x * blockDim.x + threadIdx.x;
    if (i < e) atomicAdd(&cnt[dst[i]], 1);
}

// phase 1: per-block sum of 256 counts
__global__ __launch_bounds__(256)
void scan_p1(const int* __restrict__ cnt, int n, int* __restrict__ bsum)
{
    __shared__ int sm[256];
    int i = blockIdx.x * 256 + threadIdx.x;
    sm[threadIdx.x] = (i < n) ? cnt[i] : 0;
    __syncthreads();
    #pragma unroll
    for (int off = 128; off > 0; off >>= 1) {
        if (threadIdx.x < off) sm[threadIdx.x] += sm[threadIdx.x + off];
        __syncthreads();
    }
    if (threadIdx.x == 0) bsum[blockIdx.x] = sm[0];
}

// phase 2: exclusive scan of block sums (nb <= 256) in one block
__global__ __launch_bounds__(256)
void scan_p2(int* __restrict__ bsum, int nb)
{
    __shared__ int sm[256];
    int v = (threadIdx.x < nb) ? bsum[threadIdx.x] : 0;
    sm[threadIdx.x] = v;
    __syncthreads();
    int acc = v;
    for (int off = 1; off < 256; off <<= 1) {
        int t = (threadIdx.x >= off) ? sm[threadIdx.x - off] : 0;
        __syncthreads();
        acc += t;
        sm[threadIdx.x] = acc;
        __syncthreads();
    }
    if (threadIdx.x < nb) bsum[threadIdx.x] = acc - v;  // exclusive
}

// phase 3: per-block exclusive scan + block offset -> row_ptr
__global__ __launch_bounds__(256)
void scan_p3(const int* __restrict__ cnt, const int* __restrict__ bsum,
             int* __restrict__ row_ptr, int n, int e)
{
    __shared__ int sm[256];
    int i = blockIdx.x * 256 + threadIdx.x;
    int v = (i < n) ? cnt[i] : 0;
    sm[threadIdx.x] = v;
    __syncthreads();
    int acc = v;
    for (int off = 1; off < 256; off <<= 1) {
        int t = (threadIdx.x >= off) ? sm[threadIdx.x - off] : 0;
        __syncthreads();
        acc += t;
        sm[threadIdx.x] = acc;
        __syncthreads();
    }
    if (i < n) row_ptr[i] = bsum[blockIdx.x] + acc - v;
    if (blockIdx.x == 0 && threadIdx.x == 0) row_ptr[n] = e;
}

__global__ void scatter_kernel(const int* __restrict__ src, const int* __restrict__ dst, int e,
                               const int* __restrict__ row_ptr, int* __restrict__ cursor,
                               int* __restrict__ csr_src)
{
    int i = blockIdx.x * blockDim.x + threadIdx.x;
    if (i < e) {
        int d = dst[i];
        int pos = atomicAdd(&cursor[d], 1);
        csr_src[row_ptr[d] + pos] = src[i];
    }
}

// ---------------------------------------------------------------------------
// Attention: one block (128 threads) per destination node.
// thread = output channel; wave 0 = head 0 (ch 0..63), wave 1 = head 1.
// Online softmax over incoming edges; m/l are wave-uniform after the shuffle
// reduce, so the max-update branch is wave-uniform (1 exp per edge).
// ---------------------------------------------------------------------------
__global__ __launch_bounds__(128)
void attn(const float* __restrict__ Q, const float* __restrict__ K,
          const float* __restrict__ V, const float* __restrict__ S,
          const int* __restrict__ row_ptr, const int* __restrict__ csr_src,
          float* __restrict__ out, int n, int do_relu)
{
    const int dstn = blockIdx.x;
    const int c = threadIdx.x;
    const float q = Q[dstn * D + c];
    const int beg = row_ptr[dstn];
    const int end = row_ptr[dstn + 1];

    float m = -INFINITY, l = 0.f, acc = 0.f;
    for (int i = beg; i < end; ++i) {
        int s = csr_src[i];
        float kv = K[s * D + c];
        float part = q * kv;
        #pragma unroll
        for (int off = 32; off >= 1; off >>= 1)
            part += __shfl_xor(part, off, 64);
        float alpha = part * 0.125f;              // / sqrt(64)
        float vv = V[s * D + c];
        if (alpha > m) {                           // wave-uniform branch
            float corr = __expf(m - alpha);        // exp(-inf)=0 first iter
            l   = l * corr + 1.f;
            acc = acc * corr + vv;
            m   = alpha;
        } else {
            float p = __expf(alpha - m);
            l   += p;
            acc += p * vv;
        }
    }
    float res = (l > 0.f) ? (acc / l) : 0.f;      // empty segment -> 0 (matches JAX)
    res += S[dstn * D + c];
    if (do_relu) res = fmaxf(res, 0.f);
    out[dstn * D + c] = res;
}

// ---------------------------------------------------------------------------
extern "C" void kernel_launch(void* const* d_in, const int* in_sizes, int n_in,
                              void* d_out, int out_size, void* d_ws, size_t ws_size,
                              hipStream_t stream)
{
    const float* x    = (const float*)d_in[0];
    const int*   edge = (const int*)d_in[1];
    const int n = in_sizes[0] / D;
    const int e = in_sizes[1] / 2;
    const int* srcv = edge;
    const int* dstv = edge + e;

    const float* Wq1 = (const float*)d_in[2];  const float* bq1 = (const float*)d_in[3];
    const float* Wk1 = (const float*)d_in[4];  const float* bk1 = (const float*)d_in[5];
    const float* Wv1 = (const float*)d_in[6];  const float* bv1 = (const float*)d_in[7];
    const float* Ws1 = (const float*)d_in[8];  const float* bs1 = (const float*)d_in[9];
    const float* Wq2 = (const float*)d_in[10]; const float* bq2 = (const float*)d_in[11];
    const float* Wk2 = (const float*)d_in[12]; const float* bk2 = (const float*)d_in[13];
    const float* Wv2 = (const float*)d_in[14]; const float* bv2 = (const float*)d_in[15];
    const float* Ws2 = (const float*)d_in[16]; const float* bs2 = (const float*)d_in[17];

    // workspace layout
    char* wsb = (char*)d_ws;
    size_t off = 0;
    auto alloc = [&](size_t bytes) -> void* {
        void* p = wsb + off;
        off += (bytes + 255) & ~(size_t)255;
        return p;
    };
    float* Qb  = (float*)alloc((size_t)n * D * sizeof(float));
    float* Kb  = (float*)alloc((size_t)n * D * sizeof(float));
    float* Vb  = (float*)alloc((size_t)n * D * sizeof(float));
    float* Sb  = (float*)alloc((size_t)n * D * sizeof(float));
    float* Hb  = (float*)alloc((size_t)n * D * sizeof(float));
    int* cnt     = (int*)alloc((size_t)n * sizeof(int));
    int* cursor  = (int*)alloc((size_t)n * sizeof(int));
    int* row_ptr = (int*)alloc((size_t)(n + 1) * sizeof(int));
    int* bsum    = (int*)alloc(1024 * sizeof(int));
    int* csr_src = (int*)alloc((size_t)e * sizeof(int));
    (void)ws_size; (void)n_in; (void)out_size;

    const int nb = (n + 255) / 256;   // 196 blocks for n=50000

    // ---- CSR build (shared by both layers) ----
    hipMemsetAsync(cnt, 0, (size_t)n * sizeof(int), stream);
    hipMemsetAsync(cursor, 0, (size_t)n * sizeof(int), stream);
    degree_hist<<<(e + 255) / 256, 256, 0, stream>>>(dstv, e, cnt);
    scan_p1<<<nb, 256, 0, stream>>>(cnt, n, bsum);
    scan_p2<<<1, 256, 0, stream>>>(bsum, nb);
    scan_p3<<<nb, 256, 0, stream>>>(cnt, bsum, row_ptr, n, e);
    scatter_kernel<<<(e + 255) / 256, 256, 0, stream>>>(srcv, dstv, e, row_ptr, cursor, csr_src);

    dim3 ggrid((n + 63) / 64, 4);

    // ---- layer 1 ----
    gemm4<<<ggrid, 256, 0, stream>>>(x, n,
        Wq1, bq1, Qb, Wk1, bk1, Kb, Wv1, bv1, Vb, Ws1, bs1, Sb);
    attn<<<n, 128, 0, stream>>>(Qb, Kb, Vb, Sb, row_ptr, csr_src, Hb, n, 1);

    // ---- layer 2 ----
    gemm4<<<ggrid, 256, 0, stream>>>(Hb, n,
        Wq2, bq2, Qb, Wk2, bk2, Kb, Wv2, bv2, Vb, Ws2, bs2, Sb);
    attn<<<n, 128, 0, stream>>>(Qb, Kb, Vb, Sb, row_ptr, csr_src, (float*)d_out, n, 0);
}

// Round 3
// 544.053 us; speedup vs baseline: 1.4008x; 1.1045x over previous
//
#include <hip/hip_runtime.h>
#include <math.h>

#define D 128

__device__ inline unsigned bf16pair(float a, float b) {
    unsigned ua = __float_as_uint(a); ua = (ua + 0x7fff + ((ua >> 16) & 1)) >> 16;
    unsigned ub = __float_as_uint(b); ub = (ub + 0x7fff + ((ub >> 16) & 1)) >> 16;
    return ua | (ub << 16);
}
__device__ inline float bf16lo(unsigned w) { return __uint_as_float(w << 16); }
__device__ inline float bf16hi(unsigned w) { return __uint_as_float(w & 0xffff0000u); }

// ---------------------------------------------------------------------------
// GEMM: O_w = X @ W_w + b_w for the 4 weights (Q,K,V,Skip) of one layer.
// Q,S written fp32; K,V written as packed bf16 into KVu:
//   KVu[row*128 + 2p]   = (k[2p],k[2p+1])   (bf16x2)
//   KVu[row*128 + 2p+1] = (v[2p],v[2p+1])
// so one uint2 per lane covers 2 K + 2 V channels, 512 B/row contiguous.
// ---------------------------------------------------------------------------
__global__ __launch_bounds__(256)
void gemm4(const float* __restrict__ X, int n,
           const float* __restrict__ Wq, const float* __restrict__ bq, float* __restrict__ Qb,
           const float* __restrict__ Wk, const float* __restrict__ bk,
           const float* __restrict__ Wv, const float* __restrict__ bv, unsigned* __restrict__ KVu,
           const float* __restrict__ Ws, const float* __restrict__ bs, float* __restrict__ Sb)
{
    const float* W; const float* b;
    const int mode = blockIdx.y;      // 0=Q 1=K 2=V 3=S
    switch (mode) {
        case 0:  W = Wq; b = bq; break;
        case 1:  W = Wk; b = bk; break;
        case 2:  W = Wv; b = bv; break;
        default: W = Ws; b = bs; break;
    }

    __shared__ float Xs[16][64];    // [k][row]
    __shared__ float Wt[16][128];   // [k][col]

    const int tid  = threadIdx.x;
    const int trow = tid >> 5;      // 0..7
    const int tcol = tid & 31;      // 0..31
    const int r0   = trow * 8;
    const int c0   = tcol * 4;
    const int rowBase = blockIdx.x * 64;

    float acc[8][4];
    #pragma unroll
    for (int r = 0; r < 8; ++r)
        #pragma unroll
        for (int j = 0; j < 4; ++j) acc[r][j] = 0.f;

    for (int k0 = 0; k0 < D; k0 += 16) {
        {
            int r = tid >> 2;
            int q = tid & 3;
            int row = rowBase + r;
            float4 xv = make_float4(0.f, 0.f, 0.f, 0.f);
            if (row < n) xv = *(const float4*)&X[row * D + k0 + q * 4];
            Xs[q*4+0][r] = xv.x; Xs[q*4+1][r] = xv.y;
            Xs[q*4+2][r] = xv.z; Xs[q*4+3][r] = xv.w;
        }
        {
            #pragma unroll
            for (int i = 0; i < 2; ++i) {
                int f4 = tid * 2 + i;
                int kk = f4 >> 5;
                int c  = (f4 & 31) * 4;
                *(float4*)&Wt[kk][c] = *(const float4*)&W[(k0 + kk) * D + c];
            }
        }
        __syncthreads();

        #pragma unroll
        for (int kk = 0; kk < 16; ++kk) {
            float4 a0 = *(const float4*)&Xs[kk][r0];
            float4 a1 = *(const float4*)&Xs[kk][r0 + 4];
            float4 wv = *(const float4*)&Wt[kk][c0];
            float a[8] = {a0.x, a0.y, a0.z, a0.w, a1.x, a1.y, a1.z, a1.w};
            float w[4] = {wv.x, wv.y, wv.z, wv.w};
            #pragma unroll
            for (int r = 0; r < 8; ++r)
                #pragma unroll
                for (int j = 0; j < 4; ++j)
                    acc[r][j] += a[r] * w[j];
        }
        __syncthreads();
    }

    const float b0 = b[c0], b1 = b[c0+1], b2 = b[c0+2], b3 = b[c0+3];
    #pragma unroll
    for (int r = 0; r < 8; ++r) {
        int row = rowBase + r0 + r;
        if (row >= n) continue;
        float o0 = acc[r][0] + b0, o1 = acc[r][1] + b1;
        float o2 = acc[r][2] + b2, o3 = acc[r][3] + b3;
        if (mode == 0) {
            *(float4*)&Qb[row * D + c0] = make_float4(o0, o1, o2, o3);
        } else if (mode == 3) {
            *(float4*)&Sb[row * D + c0] = make_float4(o0, o1, o2, o3);
        } else {
            unsigned lo = bf16pair(o0, o1);
            unsigned hi = bf16pair(o2, o3);
            int base = row * 128 + c0 + (mode == 2 ? 1 : 0);  // V at odd slots
            KVu[base]     = lo;
            KVu[base + 2] = hi;
        }
    }
}

// ---------------------------------------------------------------------------
// CSR build: in-degree histogram -> 3-phase parallel exclusive scan -> scatter
// ---------------------------------------------------------------------------
__global__ void degree_hist(const int* __restrict__ dst, int e, int* __restrict__ cnt)
{
    int i = blockIdx.x * blockDim.x + threadIdx.x;
    if (i < e) atomicAdd(&cnt[dst[i]], 1);
}

__global__ __launch_bounds__(256)
void scan_p1(const int* __restrict__ cnt, int n, int* __restrict__ bsum)
{
    __shared__ int sm[256];
    int i = blockIdx.x * 256 + threadIdx.x;
    sm[threadIdx.x] = (i < n) ? cnt[i] : 0;
    __syncthreads();
    #pragma unroll
    for (int off = 128; off > 0; off >>= 1) {
        if (threadIdx.x < off) sm[threadIdx.x] += sm[threadIdx.x + off];
        __syncthreads();
    }
    if (threadIdx.x == 0) bsum[blockIdx.x] = sm[0];
}

__global__ __launch_bounds__(256)
void scan_p2(int* __restrict__ bsum, int nb)
{
    __shared__ int sm[256];
    int v = (threadIdx.x < nb) ? bsum[threadIdx.x] : 0;
    sm[threadIdx.x] = v;
    __syncthreads();
    int acc = v;
    for (int off = 1; off < 256; off <<= 1) {
        int t = (threadIdx.x >= off) ? sm[threadIdx.x - off] : 0;
        __syncthreads();
        acc += t;
        sm[threadIdx.x] = acc;
        __syncthreads();
    }
    if (threadIdx.x < nb) bsum[threadIdx.x] = acc - v;
}

__global__ __launch_bounds__(256)
void scan_p3(const int* __restrict__ cnt, const int* __restrict__ bsum,
             int* __restrict__ row_ptr, int n, int e)
{
    __shared__ int sm[256];
    int i = blockIdx.x * 256 + threadIdx.x;
    int v = (i < n) ? cnt[i] : 0;
    sm[threadIdx.x] = v;
    __syncthreads();
    int acc = v;
    for (int off = 1; off < 256; off <<= 1) {
        int t = (threadIdx.x >= off) ? sm[threadIdx.x - off] : 0;
        __syncthreads();
        acc += t;
        sm[threadIdx.x] = acc;
        __syncthreads();
    }
    if (i < n) row_ptr[i] = bsum[blockIdx.x] + acc - v;
    if (blockIdx.x == 0 && threadIdx.x == 0) row_ptr[n] = e;
}

__global__ void scatter_kernel(const int* __restrict__ src, const int* __restrict__ dst, int e,
                               const int* __restrict__ row_ptr, int* __restrict__ cursor,
                               int* __restrict__ csr_src)
{
    int i = blockIdx.x * blockDim.x + threadIdx.x;
    if (i < e) {
        int d = dst[i];
        int pos = atomicAdd(&cursor[d], 1);
        csr_src[row_ptr[d] + pos] = src[i];
    }
}

// ---------------------------------------------------------------------------
// Attention: ONE WAVE per destination node (block = 256 = 4 nodes).
// lane i holds channels 2i,2i+1 -> lanes 0..31 = head 0, lanes 32..63 = head 1.
// Per edge: one coalesced 512B uint2 load (2 K ch + 2 V ch bf16), 5-shuffle
// half-wave reduce, branchless online softmax. Next edge's KV prefetched.
// ---------------------------------------------------------------------------
__global__ __launch_bounds__(256)
void attn(const float* __restrict__ Q, const uint2* __restrict__ KV,
          const float* __restrict__ S,
          const int* __restrict__ row_ptr, const int* __restrict__ csr_src,
          float* __restrict__ out, int n, int do_relu)
{
    const int node = blockIdx.x * 4 + (threadIdx.x >> 6);
    if (node >= n) return;
    const int lane = threadIdx.x & 63;

    const float2 q = *(const float2*)&Q[node * D + 2 * lane];
    const int beg = row_ptr[node];
    const int end = row_ptr[node + 1];

    float m = -INFINITY, l = 0.f, a0 = 0.f, a1 = 0.f;

    int i = beg;
    uint2 w = make_uint2(0, 0);
    if (i < end) {
        int s = csr_src[i];
        w = KV[(size_t)s * 64 + lane];
    }
    while (i < end) {
        uint2 wc = w;
        int inext = i + 1;
        if (inext < end) {
            int s2 = csr_src[inext];
            w = KV[(size_t)s2 * 64 + lane];
        }
        float k0 = bf16lo(wc.x), k1 = bf16hi(wc.x);
        float v0 = bf16lo(wc.y), v1 = bf16hi(wc.y);
        float part = q.x * k0 + q.y * k1;
        part += __shfl_xor(part, 16, 64);
        part += __shfl_xor(part, 8, 64);
        part += __shfl_xor(part, 4, 64);
        part += __shfl_xor(part, 2, 64);
        part += __shfl_xor(part, 1, 64);
        float alpha = part * 0.125f;              // / sqrt(64)
        float mn = fmaxf(m, alpha);
        float corr = __expf(m - mn);              // exp(-inf)=0 first iter
        float p = __expf(alpha - mn);
        l  = l  * corr + p;
        a0 = a0 * corr + p * v0;
        a1 = a1 * corr + p * v1;
        m = mn;
        i = inext;
    }
    float inv = (l > 0.f) ? (1.f / l) : 0.f;      // empty segment -> 0
    const float2 s2v = *(const float2*)&S[node * D + 2 * lane];
    float r0 = a0 * inv + s2v.x;
    float r1 = a1 * inv + s2v.y;
    if (do_relu) { r0 = fmaxf(r0, 0.f); r1 = fmaxf(r1, 0.f); }
    *(float2*)&out[node * D + 2 * lane] = make_float2(r0, r1);
}

// ---------------------------------------------------------------------------
extern "C" void kernel_launch(void* const* d_in, const int* in_sizes, int n_in,
                              void* d_out, int out_size, void* d_ws, size_t ws_size,
                              hipStream_t stream)
{
    const float* x    = (const float*)d_in[0];
    const int*   edge = (const int*)d_in[1];
    const int n = in_sizes[0] / D;
    const int e = in_sizes[1] / 2;
    const int* srcv = edge;
    const int* dstv = edge + e;

    const float* Wq1 = (const float*)d_in[2];  const float* bq1 = (const float*)d_in[3];
    const float* Wk1 = (const float*)d_in[4];  const float* bk1 = (const float*)d_in[5];
    const float* Wv1 = (const float*)d_in[6];  const float* bv1 = (const float*)d_in[7];
    const float* Ws1 = (const float*)d_in[8];  const float* bs1 = (const float*)d_in[9];
    const float* Wq2 = (const float*)d_in[10]; const float* bq2 = (const float*)d_in[11];
    const float* Wk2 = (const float*)d_in[12]; const float* bk2 = (const float*)d_in[13];
    const float* Wv2 = (const float*)d_in[14]; const float* bv2 = (const float*)d_in[15];
    const float* Ws2 = (const float*)d_in[16]; const float* bs2 = (const float*)d_in[17];

    char* wsb = (char*)d_ws;
    size_t off = 0;
    auto alloc = [&](size_t bytes) -> void* {
        void* p = wsb + off;
        off += (bytes + 255) & ~(size_t)255;
        return p;
    };
    float*    Qb  = (float*)alloc((size_t)n * D * sizeof(float));
    float*    Sb  = (float*)alloc((size_t)n * D * sizeof(float));
    unsigned* KVu = (unsigned*)alloc((size_t)n * 128 * sizeof(unsigned));
    float*    Hb  = (float*)alloc((size_t)n * D * sizeof(float));
    int* cnt     = (int*)alloc((size_t)n * sizeof(int));
    int* cursor  = (int*)alloc((size_t)n * sizeof(int));
    int* row_ptr = (int*)alloc((size_t)(n + 1) * sizeof(int));
    int* bsum    = (int*)alloc(1024 * sizeof(int));
    int* csr_src = (int*)alloc((size_t)e * sizeof(int));
    (void)ws_size; (void)n_in; (void)out_size;

    const int nb = (n + 255) / 256;

    // ---- CSR build (shared by both layers) ----
    hipMemsetAsync(cnt, 0, (size_t)n * sizeof(int), stream);
    hipMemsetAsync(cursor, 0, (size_t)n * sizeof(int), stream);
    degree_hist<<<(e + 255) / 256, 256, 0, stream>>>(dstv, e, cnt);
    scan_p1<<<nb, 256, 0, stream>>>(cnt, n, bsum);
    scan_p2<<<1, 256, 0, stream>>>(bsum, nb);
    scan_p3<<<nb, 256, 0, stream>>>(cnt, bsum, row_ptr, n, e);
    scatter_kernel<<<(e + 255) / 256, 256, 0, stream>>>(srcv, dstv, e, row_ptr, cursor, csr_src);

    dim3 ggrid((n + 63) / 64, 4);
    const int ablocks = (n + 3) / 4;

    // ---- layer 1 ----
    gemm4<<<ggrid, 256, 0, stream>>>(x, n,
        Wq1, bq1, Qb, Wk1, bk1, Wv1, bv1, KVu, Ws1, bs1, Sb);
    attn<<<ablocks, 256, 0, stream>>>(Qb, (const uint2*)KVu, Sb, row_ptr, csr_src, Hb, n, 1);

    // ---- layer 2 ----
    gemm4<<<ggrid, 256, 0, stream>>>(Hb, n,
        Wq2, bq2, Qb, Wk2, bk2, Wv2, bv2, KVu, Ws2, bs2, Sb);
    attn<<<ablocks, 256, 0, stream>>>(Qb, (const uint2*)KVu, Sb, row_ptr, csr_src, (float*)d_out, n, 0);
}

// Round 4
// 499.241 us; speedup vs baseline: 1.5265x; 1.0898x over previous
//
#include <hip/hip_runtime.h>
#include <math.h>

#define D 128

typedef float  f32x4  __attribute__((ext_vector_type(4)));
typedef short  bf16x8 __attribute__((ext_vector_type(8)));

__device__ inline unsigned short bf16r(float f) {
    unsigned u = __float_as_uint(f);
    u = (u + 0x7fff + ((u >> 16) & 1)) >> 16;
    return (unsigned short)u;
}
__device__ inline unsigned bf16pair(float a, float b) {
    return (unsigned)bf16r(a) | ((unsigned)bf16r(b) << 16);
}
__device__ inline float bf16lo(unsigned w) { return __uint_as_float(w << 16); }
__device__ inline float bf16hi(unsigned w) { return __uint_as_float(w & 0xffff0000u); }

// ---------------------------------------------------------------------------
// convert X (fp32) -> bf16 packed pairs. thread i packs cols 2i,2i+1 of a row.
// ---------------------------------------------------------------------------
__global__ void convert_x(const float* __restrict__ X, unsigned* __restrict__ Xb, int npairs)
{
    int i = blockIdx.x * blockDim.x + threadIdx.x;
    if (i < npairs) {
        float2 v = *(const float2*)&X[2 * i];
        Xb[i] = bf16pair(v.x, v.y);
    }
}

// ---------------------------------------------------------------------------
// convert + transpose 8 weight matrices [k][n] fp32 -> [n][k] bf16.
// blockIdx.x = weight index.
// ---------------------------------------------------------------------------
__global__ __launch_bounds__(256)
void convert_w(const float* __restrict__ W0, const float* __restrict__ W1,
               const float* __restrict__ W2, const float* __restrict__ W3,
               const float* __restrict__ W4, const float* __restrict__ W5,
               const float* __restrict__ W6, const float* __restrict__ W7,
               unsigned short* __restrict__ Wt)
{
    const float* Ws[8] = {W0, W1, W2, W3, W4, W5, W6, W7};
    const float* W = Ws[blockIdx.x];
    unsigned short* o = Wt + blockIdx.x * 16384;
    for (int i = threadIdx.x; i < 16384; i += 256) {
        int k = i >> 7, c = i & 127;
        o[c * 128 + k] = bf16r(W[i]);       // coalesced read, scattered 2B write (tiny)
    }
}

// ---------------------------------------------------------------------------
// MFMA GEMM: O_w = Xb @ W_w^T-stored + b_w.  Xb: [n][128] bf16. Wt: [col][k] bf16.
// Block: 256 thr = 4 waves, 128x128 output tile; wave = 64x64 (4x4 of 16x16x32).
// blockIdx.x = weight (0=Q,1=K,2=V,3=S), blockIdx.y = row tile (weight fastest
// so one A-tile's 4 consumers are adjacent in dispatch -> L2-hot).
// Q,S stored fp32; K,V stored bf16 planes.
// LDS stride padded to 136 bf16 -> frag reads are <=2-way bank aliased (free).
// ---------------------------------------------------------------------------
__global__ __launch_bounds__(256)
void gemm_mfma(const unsigned short* __restrict__ Xb, int n,
               const unsigned short* __restrict__ Wtall,
               const float* __restrict__ bq, const float* __restrict__ bk,
               const float* __restrict__ bv, const float* __restrict__ bs,
               float* __restrict__ Qb, unsigned short* __restrict__ Kp,
               unsigned short* __restrict__ Vp, float* __restrict__ Sb)
{
    const int w = blockIdx.x;
    const int rowBase = blockIdx.y * 128;
    const unsigned short* W = Wtall + w * 16384;
    const float* bias = (w == 0) ? bq : (w == 1) ? bk : (w == 2) ? bv : bs;

    __shared__ unsigned short Asm[128 * 136];
    __shared__ unsigned short Bsm[128 * 136];

    const int tid  = threadIdx.x;
    const int wave = tid >> 6;
    const int lane = tid & 63;
    const int wr   = wave >> 1;       // 0..1 row half
    const int wc   = wave & 1;        // 0..1 col half
    const int q16  = lane >> 4;       // 0..3
    const int r16  = lane & 15;       // 0..15

    // ---- stage A (row tile) and B (weight) into LDS, 16B per thread-iter ----
    #pragma unroll
    for (int i = 0; i < 8; ++i) {
        int g = tid + 256 * i;            // chunk id 0..2047 (16B chunks)
        int m = g >> 4, c = g & 15;
        int row = rowBase + m; if (row >= n) row = n - 1;
        uint4 da = *(const uint4*)(Xb + (size_t)row * 128 + c * 8);
        *(uint4*)&Asm[m * 136 + c * 8] = da;
        uint4 db = *(const uint4*)(W + (size_t)m * 128 + c * 8);
        *(uint4*)&Bsm[m * 136 + c * 8] = db;
    }
    __syncthreads();

    f32x4 acc[4][4];
    #pragma unroll
    for (int mi = 0; mi < 4; ++mi)
        #pragma unroll
        for (int nj = 0; nj < 4; ++nj) acc[mi][nj] = (f32x4)(0.f);

    #pragma unroll
    for (int kc = 0; kc < 4; ++kc) {
        bf16x8 a[4], b[4];
        #pragma unroll
        for (int mi = 0; mi < 4; ++mi)
            a[mi] = *(const bf16x8*)&Asm[(wr * 64 + mi * 16 + r16) * 136 + kc * 32 + q16 * 8];
        #pragma unroll
        for (int nj = 0; nj < 4; ++nj)
            b[nj] = *(const bf16x8*)&Bsm[(wc * 64 + nj * 16 + r16) * 136 + kc * 32 + q16 * 8];
        #pragma unroll
        for (int mi = 0; mi < 4; ++mi)
            #pragma unroll
            for (int nj = 0; nj < 4; ++nj)
                acc[mi][nj] = __builtin_amdgcn_mfma_f32_16x16x32_bf16(a[mi], b[nj], acc[mi][nj], 0, 0, 0);
    }

    // ---- epilogue: C/D layout col=lane&15, row=(lane>>4)*4+reg ----
    #pragma unroll
    for (int nj = 0; nj < 4; ++nj) {
        const int col = wc * 64 + nj * 16 + r16;
        const float bv4 = bias[col];
        #pragma unroll
        for (int mi = 0; mi < 4; ++mi) {
            #pragma unroll
            for (int r = 0; r < 4; ++r) {
                int row = rowBase + wr * 64 + mi * 16 + q16 * 4 + r;
                if (row >= n) continue;
                float val = acc[mi][nj][r] + bv4;
                size_t off = (size_t)row * 128 + col;
                if (w == 0)      Qb[off] = val;
                else if (w == 3) Sb[off] = val;
                else if (w == 1) Kp[off] = bf16r(val);
                else             Vp[off] = bf16r(val);
            }
        }
    }
}

// ---------------------------------------------------------------------------
// CSR build: in-degree histogram -> 3-phase parallel exclusive scan -> scatter
// ---------------------------------------------------------------------------
__global__ void degree_hist(const int* __restrict__ dst, int e, int* __restrict__ cnt)
{
    int i = blockIdx.x * blockDim.x + threadIdx.x;
    if (i < e) atomicAdd(&cnt[dst[i]], 1);
}

__global__ __launch_bounds__(256)
void scan_p1(const int* __restrict__ cnt, int n, int* __restrict__ bsum)
{
    __shared__ int sm[256];
    int i = blockIdx.x * 256 + threadIdx.x;
    sm[threadIdx.x] = (i < n) ? cnt[i] : 0;
    __syncthreads();
    #pragma unroll
    for (int off = 128; off > 0; off >>= 1) {
        if (threadIdx.x < off) sm[threadIdx.x] += sm[threadIdx.x + off];
        __syncthreads();
    }
    if (threadIdx.x == 0) bsum[blockIdx.x] = sm[0];
}

__global__ __launch_bounds__(256)
void scan_p2(int* __restrict__ bsum, int nb)
{
    __shared__ int sm[256];
    int v = (threadIdx.x < nb) ? bsum[threadIdx.x] : 0;
    sm[threadIdx.x] = v;
    __syncthreads();
    int acc = v;
    for (int off = 1; off < 256; off <<= 1) {
        int t = (threadIdx.x >= off) ? sm[threadIdx.x - off] : 0;
        __syncthreads();
        acc += t;
        sm[threadIdx.x] = acc;
        __syncthreads();
    }
    if (threadIdx.x < nb) bsum[threadIdx.x] = acc - v;
}

__global__ __launch_bounds__(256)
void scan_p3(const int* __restrict__ cnt, const int* __restrict__ bsum,
             int* __restrict__ row_ptr, int n, int e)
{
    __shared__ int sm[256];
    int i = blockIdx.x * 256 + threadIdx.x;
    int v = (i < n) ? cnt[i] : 0;
    sm[threadIdx.x] = v;
    __syncthreads();
    int acc = v;
    for (int off = 1; off < 256; off <<= 1) {
        int t = (threadIdx.x >= off) ? sm[threadIdx.x - off] : 0;
        __syncthreads();
        acc += t;
        sm[threadIdx.x] = acc;
        __syncthreads();
    }
    if (i < n) row_ptr[i] = bsum[blockIdx.x] + acc - v;
    if (blockIdx.x == 0 && threadIdx.x == 0) row_ptr[n] = e;
}

__global__ void scatter_kernel(const int* __restrict__ src, const int* __restrict__ dst, int e,
                               const int* __restrict__ row_ptr, int* __restrict__ cursor,
                               int* __restrict__ csr_src)
{
    int i = blockIdx.x * blockDim.x + threadIdx.x;
    if (i < e) {
        int d = dst[i];
        int pos = atomicAdd(&cursor[d], 1);
        csr_src[row_ptr[d] + pos] = src[i];
    }
}

// ---------------------------------------------------------------------------
// Attention: ONE WAVE per destination node (block = 256 = 4 nodes).
// lane i holds channels 2i,2i+1 -> lanes 0..31 = head 0, lanes 32..63 = head 1.
// Per edge: two coalesced 256B uint loads (K pair + V pair, bf16), 5-shuffle
// half-wave reduce, online softmax. Next edge's K/V prefetched.
// Writes bf16 (layer 1 -> GEMM input) or fp32 (final).
// ---------------------------------------------------------------------------
__global__ __launch_bounds__(256)
void attn(const float* __restrict__ Q, const unsigned* __restrict__ Ku,
          const unsigned* __restrict__ Vu, const float* __restrict__ S,
          const int* __restrict__ row_ptr, const int* __restrict__ csr_src,
          float* __restrict__ outf, unsigned* __restrict__ outb,
          int n, int do_relu)
{
    const int node = blockIdx.x * 4 + (threadIdx.x >> 6);
    if (node >= n) return;
    const int lane = threadIdx.x & 63;

    const float2 q = *(const float2*)&Q[node * D + 2 * lane];
    const int beg = row_ptr[node];
    const int end = row_ptr[node + 1];

    float m = -INFINITY, l = 0.f, a0 = 0.f, a1 = 0.f;

    int i = beg;
    unsigned kw = 0, vw = 0;
    if (i < end) {
        int s = csr_src[i];
        kw = Ku[(size_t)s * 64 + lane];
        vw = Vu[(size_t)s * 64 + lane];
    }
    while (i < end) {
        unsigned kc = kw, vc = vw;
        int inext = i + 1;
        if (inext < end) {
            int s2 = csr_src[inext];
            kw = Ku[(size_t)s2 * 64 + lane];
            vw = Vu[(size_t)s2 * 64 + lane];
        }
        float k0 = bf16lo(kc), k1 = bf16hi(kc);
        float v0 = bf16lo(vc), v1 = bf16hi(vc);
        float part = q.x * k0 + q.y * k1;
        part += __shfl_xor(part, 16, 64);
        part += __shfl_xor(part, 8, 64);
        part += __shfl_xor(part, 4, 64);
        part += __shfl_xor(part, 2, 64);
        part += __shfl_xor(part, 1, 64);
        float alpha = part * 0.125f;              // / sqrt(64)
        float mn = fmaxf(m, alpha);
        float corr = __expf(m - mn);              // exp(-inf)=0 first iter
        float p = __expf(alpha - mn);
        l  = l  * corr + p;
        a0 = a0 * corr + p * v0;
        a1 = a1 * corr + p * v1;
        m = mn;
        i = inext;
    }
    float inv = (l > 0.f) ? (1.f / l) : 0.f;      // empty segment -> 0
    const float2 s2v = *(const float2*)&S[node * D + 2 * lane];
    float r0 = a0 * inv + s2v.x;
    float r1 = a1 * inv + s2v.y;
    if (do_relu) { r0 = fmaxf(r0, 0.f); r1 = fmaxf(r1, 0.f); }
    if (outb) outb[(size_t)node * 64 + lane] = bf16pair(r0, r1);
    else      *(float2*)&outf[node * D + 2 * lane] = make_float2(r0, r1);
}

// ---------------------------------------------------------------------------
extern "C" void kernel_launch(void* const* d_in, const int* in_sizes, int n_in,
                              void* d_out, int out_size, void* d_ws, size_t ws_size,
                              hipStream_t stream)
{
    const float* x    = (const float*)d_in[0];
    const int*   edge = (const int*)d_in[1];
    const int n = in_sizes[0] / D;
    const int e = in_sizes[1] / 2;
    const int* srcv = edge;
    const int* dstv = edge + e;

    const float* Wq1 = (const float*)d_in[2];  const float* bq1 = (const float*)d_in[3];
    const float* Wk1 = (const float*)d_in[4];  const float* bk1 = (const float*)d_in[5];
    const float* Wv1 = (const float*)d_in[6];  const float* bv1 = (const float*)d_in[7];
    const float* Ws1 = (const float*)d_in[8];  const float* bs1 = (const float*)d_in[9];
    const float* Wq2 = (const float*)d_in[10]; const float* bq2 = (const float*)d_in[11];
    const float* Wk2 = (const float*)d_in[12]; const float* bk2 = (const float*)d_in[13];
    const float* Wv2 = (const float*)d_in[14]; const float* bv2 = (const float*)d_in[15];
    const float* Ws2 = (const float*)d_in[16]; const float* bs2 = (const float*)d_in[17];

    char* wsb = (char*)d_ws;
    size_t off = 0;
    auto alloc = [&](size_t bytes) -> void* {
        void* p = wsb + off;
        off += (bytes + 255) & ~(size_t)255;
        return p;
    };
    float*          Qb = (float*)alloc((size_t)n * D * sizeof(float));
    float*          Sb = (float*)alloc((size_t)n * D * sizeof(float));
    unsigned short* Kp = (unsigned short*)alloc((size_t)n * D * sizeof(unsigned short));
    unsigned short* Vp = (unsigned short*)alloc((size_t)n * D * sizeof(unsigned short));
    unsigned short* Xb = (unsigned short*)alloc((size_t)n * D * sizeof(unsigned short));
    unsigned short* Hu = (unsigned short*)alloc((size_t)n * D * sizeof(unsigned short));
    unsigned short* Wt = (unsigned short*)alloc(8 * 16384 * sizeof(unsigned short));
    int* cnt     = (int*)alloc((size_t)n * sizeof(int));
    int* cursor  = (int*)alloc((size_t)n * sizeof(int));
    int* row_ptr = (int*)alloc((size_t)(n + 1) * sizeof(int));
    int* bsum    = (int*)alloc(1024 * sizeof(int));
    int* csr_src = (int*)alloc((size_t)e * sizeof(int));
    (void)ws_size; (void)n_in; (void)out_size;

    const int nb = (n + 255) / 256;

    // ---- dtype conversions ----
    convert_x<<<(n * 64 + 255) / 256, 256, 0, stream>>>(x, (unsigned*)Xb, n * 64);
    convert_w<<<8, 256, 0, stream>>>(Wq1, Wk1, Wv1, Ws1, Wq2, Wk2, Wv2, Ws2, Wt);

    // ---- CSR build (shared by both layers) ----
    hipMemsetAsync(cnt, 0, (size_t)n * sizeof(int), stream);
    hipMemsetAsync(cursor, 0, (size_t)n * sizeof(int), stream);
    degree_hist<<<(e + 255) / 256, 256, 0, stream>>>(dstv, e, cnt);
    scan_p1<<<nb, 256, 0, stream>>>(cnt, n, bsum);
    scan_p2<<<1, 256, 0, stream>>>(bsum, nb);
    scan_p3<<<nb, 256, 0, stream>>>(cnt, bsum, row_ptr, n, e);
    scatter_kernel<<<(e + 255) / 256, 256, 0, stream>>>(srcv, dstv, e, row_ptr, cursor, csr_src);

    const dim3 ggrid(4, (n + 127) / 128);
    const int ablocks = (n + 3) / 4;

    // ---- layer 1 ----
    gemm_mfma<<<ggrid, 256, 0, stream>>>(Xb, n, Wt, bq1, bk1, bv1, bs1, Qb, Kp, Vp, Sb);
    attn<<<ablocks, 256, 0, stream>>>(Qb, (const unsigned*)Kp, (const unsigned*)Vp, Sb,
                                      row_ptr, csr_src, nullptr, (unsigned*)Hu, n, 1);

    // ---- layer 2 ----
    gemm_mfma<<<ggrid, 256, 0, stream>>>(Hu, n, Wt + 4 * 16384, bq2, bk2, bv2, bs2, Qb, Kp, Vp, Sb);
    attn<<<ablocks, 256, 0, stream>>>(Qb, (const unsigned*)Kp, (const unsigned*)Vp, Sb,
                                      row_ptr, csr_src, (float*)d_out, nullptr, n, 0);
}